// Round 1
// baseline (1822.759 us; speedup 1.0000x reference)
//
#include <hip/hip_runtime.h>
#include <cstdint>
#include <cstddef>

typedef __attribute__((ext_vector_type(8))) short short8;
typedef __attribute__((ext_vector_type(4))) float f32x4;
typedef __attribute__((ext_vector_type(2))) float f32x2;
typedef __attribute__((ext_vector_type(2))) unsigned int u32x2;

#define SEQ 2048
#define NB  64
#define HID 256
#define M_TOTAL (SEQ*NB)   // 131072

__device__ __forceinline__ unsigned short f2bf(float x){
  unsigned u = __float_as_uint(x);
  u += 0x7fffu + ((u>>16)&1u);
  return (unsigned short)(u>>16);
}

// ---------- convert x fp32 -> bf16 (4 elems/thread) ----------
__global__ void k_convert_x(const float* __restrict__ x, unsigned short* __restrict__ xb){
  size_t i = (size_t)blockIdx.x*256 + threadIdx.x;   // 0 .. 8388607
  f32x4 v = ((const f32x4*)x)[i];
  unsigned a0=f2bf(v[0]), a1=f2bf(v[1]), a2=f2bf(v[2]), a3=f2bf(v[3]);
  u32x2 o; o[0] = a0 | (a1<<16); o[1] = a2 | (a3<<16);
  ((u32x2*)xb)[i] = o;
}

// ---------- build transposed bf16 weights: BT[n][k] = W[k][n] ----------
__global__ void k_convert_w(const float* __restrict__ i2h, const float* __restrict__ h2o,
                            unsigned short* __restrict__ BT1, unsigned short* __restrict__ BT3){
  int k = blockIdx.x; int n = threadIdx.x;
  BT1[n*256+k] = f2bf(i2h[k*256+n]);   // W_xh = i2h_weight rows [0,256)
  BT3[n*256+k] = f2bf(h2o[k*256+n]);
}

// ---------- bf16 MFMA GEMM: C[M x 256] = A[M x 256] * B + bias ----------
// A row-major bf16; BT is B transposed (256 rows n, 256 cols k) bf16.
// Tile 128x128, BK=64, 256 threads = 4 waves (2x2), 16x16x32 MFMA.
__global__ __launch_bounds__(256) void k_gemm(
    const unsigned short* __restrict__ A, const unsigned short* __restrict__ BT,
    const float* __restrict__ bias, float* __restrict__ C)
{
  __shared__ __align__(16) unsigned short As[128*64];
  __shared__ __align__(16) unsigned short Bs[128*64];
  int tid = threadIdx.x;
  int bm = blockIdx.x, bn = blockIdx.y;
  int l = tid & 63, wv = tid >> 6;
  int wm = wv >> 1, wn = wv & 1;
  int lr = l & 15, lq = l >> 4;

  f32x4 acc[4][4];
  #pragma unroll
  for (int i=0;i<4;i++)
    #pragma unroll
    for (int j=0;j<4;j++) acc[i][j] = (f32x4)0.f;

  for (int kb=0; kb<4; ++kb){
    int k0 = kb*64;
    // stage A-tile (128x64) and BT-tile (128x64): 4 x 256 lanes x 16B each
    #pragma unroll
    for (int it=0; it<4; ++it){
      int f = it*256 + tid;
      int m = f >> 3;            // 8 x 16B per 128B row
      int kk = (f & 7) * 8;      // bf16 element offset in k
      short8 va = *(const short8*)(A  + (size_t)(bm*128+m)*256 + k0 + kk);
      short8 vb = *(const short8*)(BT + (size_t)(bn*128+m)*256 + k0 + kk);
      *(short8*)(As + m*64 + kk) = va;
      *(short8*)(Bs + m*64 + kk) = vb;
    }
    __syncthreads();
    #pragma unroll
    for (int kt=0; kt<2; ++kt){
      short8 af[4], bfr[4];
      #pragma unroll
      for (int mt=0;mt<4;mt++){
        int row = wm*64 + mt*16 + lr;
        af[mt] = *(const short8*)(As + row*64 + kt*32 + lq*8);
      }
      #pragma unroll
      for (int nt=0;nt<4;nt++){
        int row = wn*64 + nt*16 + lr;
        bfr[nt] = *(const short8*)(Bs + row*64 + kt*32 + lq*8);
      }
      #pragma unroll
      for (int mt=0;mt<4;mt++)
        #pragma unroll
        for (int nt=0;nt<4;nt++)
          acc[mt][nt] = __builtin_amdgcn_mfma_f32_16x16x32_bf16(af[mt], bfr[nt], acc[mt][nt], 0, 0, 0);
    }
    __syncthreads();
  }
  // epilogue: D row m = (l>>4)*4 + r, col n = l&15  (verified gfx950 C/D layout)
  #pragma unroll
  for (int nt=0;nt<4;nt++){
    int gn = bn*128 + wn*64 + nt*16 + lr;
    float bv = bias[gn];
    #pragma unroll
    for (int mt=0;mt<4;mt++){
      int gm = bm*128 + wm*64 + mt*16 + lq*4;
      #pragma unroll
      for (int r=0;r<4;r++)
        C[(size_t)(gm+r)*256 + gn] = acc[mt][nt][r] + bv;
    }
  }
}

// ---------- sequential scan: h_t = tanh(pre_t + h_{t-1} @ W_hh) ----------
// One block per batch. 1024 threads: thread (kc = tid>>8, j = tid&255) holds
// W_hh[kc*64 .. kc*64+63][j] in 64 fp32 VGPRs (W never re-read after init).
// h broadcast from LDS (wave-uniform addresses, conflict-free), 4-way
// partial reduction via LDS. Recurrence entirely fp32.
__global__ __launch_bounds__(1024, 4) void k_scan(
    const float* __restrict__ i2h,     // (512,256); W_hh = rows [256,512)
    const float* __restrict__ h0,      // (64,256)
    const float* __restrict__ pre,     // (SEQ*NB,256) fp32 (lives in d_out)
    unsigned short* __restrict__ H)    // (SEQ*NB,256) bf16 out
{
  __shared__ float hbuf[256];
  __shared__ float red[3*256];
  int b   = blockIdx.x;
  int tid = threadIdx.x;
  int kc  = tid >> 8;       // 0..3 (wave-uniform)
  int j   = tid & 255;

  f32x2 w2[32];
  const float* Wp = i2h + (size_t)(256 + kc*64)*256 + j;
  #pragma unroll
  for (int i=0;i<32;i++){
    w2[i][0] = Wp[(size_t)(2*i  )*256];
    w2[i][1] = Wp[(size_t)(2*i+1)*256];
  }
  if (tid < 256) hbuf[tid] = h0[b*256 + tid];
  __syncthreads();

  bool lead = (kc == 0);
  float pv = lead ? pre[(size_t)b*256 + j] : 0.f;

  for (int t=0; t<SEQ; ++t){
    float pn = 0.f;
    if (lead && t+1 < SEQ) pn = pre[((size_t)(t+1)*NB + b)*256 + j];  // prefetch

    const f32x2* hp = (const f32x2*)(hbuf + kc*64);
    f32x2 a2 = (f32x2)0.f;
    #pragma unroll
    for (int i=0;i<32;i++){
      f32x2 h2 = hp[i];
      a2 += w2[i]*h2;
    }
    float acc = a2[0] + a2[1];

    if (!lead) red[(kc-1)*256 + j] = acc;
    __syncthreads();
    if (lead){
      float s = acc + red[j] + red[256+j] + red[512+j] + pv;
      float e = __expf(2.f*s);           // tanh(s) = 1 - 2/(e^(2s)+1)
      float h = 1.f - 2.f/(e+1.f);
      hbuf[j] = h;
      H[((size_t)t*NB + b)*256 + j] = f2bf(h);
      pv = pn;
    }
    __syncthreads();
  }
}

extern "C" void kernel_launch(void* const* d_in, const int* in_sizes, int n_in,
                              void* d_out, int out_size, void* d_ws, size_t ws_size,
                              hipStream_t stream) {
  const float* x     = (const float*)d_in[0];
  const float* h0    = (const float*)d_in[1];
  const float* i2h   = (const float*)d_in[2];
  const float* i2h_b = (const float*)d_in[3];
  const float* h2o   = (const float*)d_in[4];
  const float* h2o_b = (const float*)d_in[5];
  float* out = (float*)d_out;

  // ws layout: [0,64MB) x_bf16, later aliased by H_bf16 (x_bf16 dead after gemm1)
  //            [64MB, +256KB) BT1, BT3
  unsigned short* xb  = (unsigned short*)d_ws;
  unsigned short* BT1 = (unsigned short*)((char*)d_ws + (size_t)M_TOTAL*HID*2);
  unsigned short* BT3 = BT1 + 256*256;

  k_convert_x<<<M_TOTAL*HID/(256*4), 256, 0, stream>>>(x, xb);
  k_convert_w<<<256, 256, 0, stream>>>(i2h, h2o, BT1, BT3);

  dim3 g1(M_TOTAL/128, 2);
  // pre = x @ W_xh + i2h_bias  -> stored in d_out (fp32), consumed by scan
  k_gemm<<<g1, 256, 0, stream>>>(xb, BT1, i2h_b, out);
  // sequential recurrence; writes H (bf16) over the xb region
  k_scan<<<NB, 1024, 0, stream>>>(i2h, h0, out, xb);
  // y = H @ W_ho + h2o_bias -> d_out (overwrites pre)
  k_gemm<<<g1, 256, 0, stream>>>(xb, BT3, h2o_b, out);
}

// Round 2
// 1653.349 us; speedup vs baseline: 1.1025x; 1.1025x over previous
//
#include <hip/hip_runtime.h>
#include <cstdint>
#include <cstddef>

typedef __attribute__((ext_vector_type(8))) short short8;
typedef __attribute__((ext_vector_type(4))) float f32x4;
typedef __attribute__((ext_vector_type(2))) float f32x2;
typedef __attribute__((ext_vector_type(2))) unsigned int u32x2;

#define SEQ 2048
#define NB  64
#define HID 256
#define M_TOTAL (SEQ*NB)   // 131072

__device__ __forceinline__ unsigned short f2bf(float x){
  unsigned u = __float_as_uint(x);
  u += 0x7fffu + ((u>>16)&1u);
  return (unsigned short)(u>>16);
}

// ---------- convert x fp32 -> bf16 (4 elems/thread) ----------
__global__ void k_convert_x(const float* __restrict__ x, unsigned short* __restrict__ xb){
  size_t i = (size_t)blockIdx.x*256 + threadIdx.x;   // 0 .. 8388607
  f32x4 v = ((const f32x4*)x)[i];
  unsigned a0=f2bf(v[0]), a1=f2bf(v[1]), a2=f2bf(v[2]), a3=f2bf(v[3]);
  u32x2 o; o[0] = a0 | (a1<<16); o[1] = a2 | (a3<<16);
  ((u32x2*)xb)[i] = o;
}

// ---------- build transposed bf16 weights: BT[n][k] = W[k][n] ----------
__global__ void k_convert_w(const float* __restrict__ i2h, const float* __restrict__ h2o,
                            unsigned short* __restrict__ BT1, unsigned short* __restrict__ BT3){
  int k = blockIdx.x; int n = threadIdx.x;
  BT1[n*256+k] = f2bf(i2h[k*256+n]);   // W_xh = i2h_weight rows [0,256)
  BT3[n*256+k] = f2bf(h2o[k*256+n]);
}

// ---------- bf16 MFMA GEMM: C[M x 256] = A[M x 256] * B + bias ----------
__global__ __launch_bounds__(256) void k_gemm(
    const unsigned short* __restrict__ A, const unsigned short* __restrict__ BT,
    const float* __restrict__ bias, float* __restrict__ C)
{
  __shared__ __align__(16) unsigned short As[128*64];
  __shared__ __align__(16) unsigned short Bs[128*64];
  int tid = threadIdx.x;
  int bm = blockIdx.x, bn = blockIdx.y;
  int l = tid & 63, wv = tid >> 6;
  int wm = wv >> 1, wn = wv & 1;
  int lr = l & 15, lq = l >> 4;

  f32x4 acc[4][4];
  #pragma unroll
  for (int i=0;i<4;i++)
    #pragma unroll
    for (int j=0;j<4;j++) acc[i][j] = (f32x4)0.f;

  for (int kb=0; kb<4; ++kb){
    int k0 = kb*64;
    #pragma unroll
    for (int it=0; it<4; ++it){
      int f = it*256 + tid;
      int m = f >> 3;
      int kk = (f & 7) * 8;
      short8 va = *(const short8*)(A  + (size_t)(bm*128+m)*256 + k0 + kk);
      short8 vb = *(const short8*)(BT + (size_t)(bn*128+m)*256 + k0 + kk);
      *(short8*)(As + m*64 + kk) = va;
      *(short8*)(Bs + m*64 + kk) = vb;
    }
    __syncthreads();
    #pragma unroll
    for (int kt=0; kt<2; ++kt){
      short8 af[4], bfr[4];
      #pragma unroll
      for (int mt=0;mt<4;mt++){
        int row = wm*64 + mt*16 + lr;
        af[mt] = *(const short8*)(As + row*64 + kt*32 + lq*8);
      }
      #pragma unroll
      for (int nt=0;nt<4;nt++){
        int row = wn*64 + nt*16 + lr;
        bfr[nt] = *(const short8*)(Bs + row*64 + kt*32 + lq*8);
      }
      #pragma unroll
      for (int mt=0;mt<4;mt++)
        #pragma unroll
        for (int nt=0;nt<4;nt++)
          acc[mt][nt] = __builtin_amdgcn_mfma_f32_16x16x32_bf16(af[mt], bfr[nt], acc[mt][nt], 0, 0, 0);
    }
    __syncthreads();
  }
  #pragma unroll
  for (int nt=0;nt<4;nt++){
    int gn = bn*128 + wn*64 + nt*16 + lr;
    float bv = bias[gn];
    #pragma unroll
    for (int mt=0;mt<4;mt++){
      int gm = bm*128 + wm*64 + mt*16 + lq*4;
      #pragma unroll
      for (int r=0;r<4;r++)
        C[(size_t)(gm+r)*256 + gn] = acc[mt][nt][r] + bv;
    }
  }
}

// ---------- sequential scan: h_t = tanh(pre_t + h_{t-1} @ W_hh) ----------
// One block per batch, 1024 threads (16 waves).
// Thread (jg = tid&63, kc = tid>>6 in [0,16)) holds W_hh[kc*16+i][jg*4+c]
// in 16 f32x4 VGPRs (reuse r=4: only 16 h-floats read per thread per step,
// broadcast ds_read_b128 since kc is wave-uniform -> conflict-free).
// LDS h-traffic: 64 KB/step (vs 256 KB in r=1 version, which was the
// measured bottleneck: 1823 cy/step at 256 B/cy return BW).
// Reduction: 16 f32x4 partials -> red[kc][j], barrier, waves 0-3 (thread j)
// sum 16 conflict-free ds_read_b32 + pre (2-step-ahead prefetched) + tanh.
__global__ __launch_bounds__(1024, 4) void k_scan(
    const float* __restrict__ i2h,     // (512,256); W_hh = rows [256,512)
    const float* __restrict__ h0,      // (64,256)
    const float* __restrict__ pre,     // (SEQ*NB,256) fp32 (lives in d_out)
    unsigned short* __restrict__ H)    // (SEQ*NB,256) bf16 out
{
  __shared__ __align__(16) float hbuf[256];
  __shared__ __align__(16) float red[16*256];   // red[kc][j], 16 KB
  int b   = blockIdx.x;
  int tid = threadIdx.x;
  int jg  = tid & 63;       // output group: j = jg*4 + c
  int kc  = tid >> 6;       // 0..15 (wave-uniform), k-chunk of 16

  // W registers: w[4*i+?][c]; w[ii] covers h[kc*16 + ii] -> outputs jg*4..+3
  f32x4 w[16];
  const float* Wp = i2h + (size_t)(256 + kc*16)*256 + jg*4;
  #pragma unroll
  for (int i=0;i<16;i++)
    w[i] = *(const f32x4*)(Wp + (size_t)i*256);

  if (tid < 256) hbuf[tid] = h0[b*256 + tid];

  // pre prefetch, 2 steps deep (leaders = waves 0-3, thread j = tid)
  float pv = 0.f, p1 = 0.f;
  if (tid < 256){
    pv = pre[(size_t)b*256 + tid];                    // t=0
    p1 = pre[((size_t)1*NB + b)*256 + tid];           // t=1
  }
  __syncthreads();

  float* myred = red + kc*256 + jg*4;

  for (int t=0; t<SEQ; ++t){
    // ---- phase A: partial matvec (all 16 waves) ----
    const f32x4* hp = (const f32x4*)(hbuf + kc*16);   // wave-uniform -> broadcast
    f32x4 acc = (f32x4)0.f;
    #pragma unroll
    for (int i=0;i<4;i++){
      f32x4 h4 = hp[i];
      acc += h4[0]*w[4*i+0];
      acc += h4[1]*w[4*i+1];
      acc += h4[2]*w[4*i+2];
      acc += h4[3]*w[4*i+3];
    }
    *(f32x4*)myred = acc;
    __syncthreads();

    // ---- phase B: reduce + tanh (waves 0-3; thread handles output j=tid) ----
    if (tid < 256){
      float p2 = (t+2 < SEQ) ? pre[((size_t)(t+2)*NB + b)*256 + tid] : 0.f;
      float s = pv;
      #pragma unroll
      for (int k2=0;k2<16;k2++) s += red[k2*256 + tid];
      float e = __expf(2.f*s);          // tanh(s) = 1 - 2/(e^(2s)+1)
      float h = 1.f - 2.f/(e+1.f);
      hbuf[tid] = h;
      H[((size_t)t*NB + b)*256 + tid] = f2bf(h);
      pv = p1; p1 = p2;
    }
    __syncthreads();
  }
}

extern "C" void kernel_launch(void* const* d_in, const int* in_sizes, int n_in,
                              void* d_out, int out_size, void* d_ws, size_t ws_size,
                              hipStream_t stream) {
  const float* x     = (const float*)d_in[0];
  const float* h0    = (const float*)d_in[1];
  const float* i2h   = (const float*)d_in[2];
  const float* i2h_b = (const float*)d_in[3];
  const float* h2o   = (const float*)d_in[4];
  const float* h2o_b = (const float*)d_in[5];
  float* out = (float*)d_out;

  // ws layout: [0,64MB) x_bf16, later aliased by H_bf16 (x_bf16 dead after gemm1)
  //            [64MB, +256KB) BT1, BT3
  unsigned short* xb  = (unsigned short*)d_ws;
  unsigned short* BT1 = (unsigned short*)((char*)d_ws + (size_t)M_TOTAL*HID*2);
  unsigned short* BT3 = BT1 + 256*256;

  k_convert_x<<<M_TOTAL*HID/(256*4), 256, 0, stream>>>(x, xb);
  k_convert_w<<<256, 256, 0, stream>>>(i2h, h2o, BT1, BT3);

  dim3 g1(M_TOTAL/128, 2);
  // pre = x @ W_xh + i2h_bias  -> stored in d_out (fp32), consumed by scan
  k_gemm<<<g1, 256, 0, stream>>>(xb, BT1, i2h_b, out);
  // sequential recurrence; writes H (bf16) over the xb region
  k_scan<<<NB, 1024, 0, stream>>>(i2h, h0, out, xb);
  // y = H @ W_ho + h2o_bias -> d_out (overwrites pre)
  k_gemm<<<g1, 256, 0, stream>>>(xb, BT3, h2o_b, out);
}